// Round 9
// baseline (324.242 us; speedup 1.0000x reference)
//
#include <hip/hip_runtime.h>
#include <math.h>

#define DD 128

static inline int cdiv(long a, long b){ return (int)((a + b - 1) / b); }

__device__ __forceinline__ unsigned bfpack(float a, float b){
  unsigned ua = __float_as_uint(a), ub = __float_as_uint(b);
  ua = (ua + 0x7fffu + ((ua >> 16) & 1u)) >> 16;
  ub = (ub + 0x7fffu + ((ub >> 16) & 1u)) >> 16;
  return ua | (ub << 16);
}

// ---------- degree count (both graphs, one launch) ----------
__global__ void k_count2(const int* __restrict__ dst_f, int Ef, int* __restrict__ cnt_f,
                         const int* __restrict__ dst_p, int Ep, int* __restrict__ cnt_p){
  int e = blockIdx.x * blockDim.x + threadIdx.x;
  if (e < Ef) atomicAdd(&cnt_f[dst_f[e]], 1);
  else { e -= Ef; if (e < Ep) atomicAdd(&cnt_p[dst_p[e]], 1); }
}

// ---------- hierarchical scan phase 1 + inv scatter (fused) ----------
__global__ __launch_bounds__(256) void k_bsum(
    const int* __restrict__ cnt_f, int nf, const int* __restrict__ cnt_p, int np,
    int* __restrict__ bsum_f, int* __restrict__ bsum_p, int nbf, int nbp,
    const int* __restrict__ unpool, int* __restrict__ inv, int npool){
  int bi = blockIdx.x;
  if (bi >= nbf + nbp){
    int i = (bi - nbf - nbp) * 256 + threadIdx.x;
    if (i < npool) inv[unpool[i]] = i;
    return;
  }
  const int* cnt; int n; int* bsum; int b;
  if (bi < nbf){ cnt = cnt_f; n = nf; bsum = bsum_f; b = bi; }
  else         { cnt = cnt_p; n = np; bsum = bsum_p; b = bi - nbf; }
  __shared__ int s[256];
  int t = threadIdx.x;
  long base = (long)b * 1024 + t * 4;
  int v = 0;
  if (base + 3 < n){ int4 q = *(const int4*)(cnt + base); v = q.x + q.y + q.z + q.w; }
  else { for (int j = 0; j < 4; j++) if (base + j < n) v += cnt[base + j]; }
  s[t] = v; __syncthreads();
  for (int off = 128; off > 0; off >>= 1){ if (t < off) s[t] += s[t + off]; __syncthreads(); }
  if (t == 0) bsum[b] = s[0];
}

// phase 2: exclusive scan of block sums
__global__ __launch_bounds__(128) void k_scan_b(int* __restrict__ bsum_f, int nbf,
                                                int* __restrict__ bsum_p, int nbp){
  __shared__ int s[128];
  int t = threadIdx.x;
  int v = (t < nbf) ? bsum_f[t] : 0;
  s[t] = v; __syncthreads();
  for (int off = 1; off < 128; off <<= 1){ int u = (t >= off) ? s[t - off] : 0; __syncthreads(); s[t] += u; __syncthreads(); }
  if (t < nbf) bsum_f[t] = s[t] - v;
  __syncthreads();
  int v2 = (t < nbp) ? bsum_p[t] : 0;
  s[t] = v2; __syncthreads();
  for (int off = 1; off < 128; off <<= 1){ int u = (t >= off) ? s[t - off] : 0; __syncthreads(); s[t] += u; __syncthreads(); }
  if (t < nbp) bsum_p[t] = s[t] - v2;
}

// phase 3: local scan -> rptr, cursor copy, dinv
__global__ __launch_bounds__(256) void k_scan_f(
    const int* __restrict__ cnt_f, int nf, const int* __restrict__ bsum_f,
    const int* __restrict__ cnt_p, int np, const int* __restrict__ bsum_p,
    int* __restrict__ rptr_f, int* __restrict__ cur_f, float* __restrict__ dinv_f,
    int* __restrict__ rptr_p, int* __restrict__ cur_p, float* __restrict__ dinv_p,
    int nbf, int Ef, int Ep){
  const int* cnt; const int* bsum; int* rptr; int* cur; float* dinv; int n; int b;
  if ((int)blockIdx.x < nbf){ cnt=cnt_f; bsum=bsum_f; rptr=rptr_f; cur=cur_f; dinv=dinv_f; n=nf; b=blockIdx.x; }
  else                      { cnt=cnt_p; bsum=bsum_p; rptr=rptr_p; cur=cur_p; dinv=dinv_p; n=np; b=blockIdx.x-nbf; }
  __shared__ int s[256];
  int t = threadIdx.x;
  long base = (long)b * 1024 + t * 4;
  int c0=0,c1=0,c2=0,c3=0;
  if (base + 3 < n){ int4 q = *(const int4*)(cnt + base); c0=q.x; c1=q.y; c2=q.z; c3=q.w; }
  else {
    if (base + 0 < n) c0 = cnt[base + 0];
    if (base + 1 < n) c1 = cnt[base + 1];
    if (base + 2 < n) c2 = cnt[base + 2];
  }
  int tsum = c0 + c1 + c2 + c3;
  s[t] = tsum; __syncthreads();
  for (int off = 1; off < 256; off <<= 1){ int u = (t >= off) ? s[t - off] : 0; __syncthreads(); s[t] += u; __syncthreads(); }
  int run = bsum[b] + s[t] - tsum;
  int r0 = run, r1 = r0 + c0, r2 = r1 + c1, r3 = r2 + c2;
  if (base + 3 < n){
    *(int4*)(rptr + base) = make_int4(r0, r1, r2, r3);
    *(int4*)(cur + base)  = make_int4(r0, r1, r2, r3);
    dinv[base + 0] = rsqrtf((float)(c0 + 1));
    dinv[base + 1] = rsqrtf((float)(c1 + 1));
    dinv[base + 2] = rsqrtf((float)(c2 + 1));
    dinv[base + 3] = rsqrtf((float)(c3 + 1));
  } else {
    if (base + 0 < n){ rptr[base+0]=r0; cur[base+0]=r0; dinv[base+0]=rsqrtf((float)(c0+1)); }
    if (base + 1 < n){ rptr[base+1]=r1; cur[base+1]=r1; dinv[base+1]=rsqrtf((float)(c1+1)); }
    if (base + 2 < n){ rptr[base+2]=r2; cur[base+2]=r2; dinv[base+2]=rsqrtf((float)(c2+1)); }
  }
  if (blockIdx.x == 0 && t == 0){ rptr_f[nf] = Ef; rptr_p[np] = Ep; }
}

// ---------- CSR fill: ONE packed store per edge ----------
__global__ void k_fill2(const int* __restrict__ src_f, const int* __restrict__ dst_f, int Ef,
                        int* __restrict__ cur_f, int4* __restrict__ ewk_f,
                        const float* __restrict__ dinv_f, const int* __restrict__ inv,
                        const int* __restrict__ src_p, const int* __restrict__ dst_p, int Ep,
                        int* __restrict__ cur_p, int2* __restrict__ ewk_p,
                        const float* __restrict__ dinv_p){
  int e = blockIdx.x * blockDim.x + threadIdx.x;
  if (e < Ef){
    int s = src_f[e];
    int p = atomicAdd(&cur_f[dst_f[e]], 1);
    ewk_f[p] = make_int4(s, inv[s], __float_as_int(dinv_f[s]), 0);
  } else {
    e -= Ef;
    if (e < Ep){
      int s = src_p[e];
      int p = atomicAdd(&cur_p[dst_p[e]], 1);
      ewk_p[p] = make_int2(s, __float_as_int(dinv_p[s]));
    }
  }
}

// ---------- GEMM 128x128 tile, 8x8 per thread: C[n,128] = A[n,128] @ W[128,128] ----------
// BF16OUT selects fp32 or packed-bf16 epilogue at compile time.
template <bool BF16OUT>
__global__ __launch_bounds__(256) void k_gemm_t(const float* __restrict__ A,
                                                const float* __restrict__ W,
                                                void* __restrict__ Cout, int n){
  __shared__ float As[16][132];   // [k][row], 132*4=528B stride (16B aligned)
  __shared__ float Ws[16][128];   // [k][col]
  const int t    = threadIdx.x;
  const int row0 = blockIdx.x * 128;
  const int tc   = t & 15;        // col group: cols tc*8 .. +7
  const int tr   = t >> 4;        // row group: rows tr*8 .. +7
  const int sr   = t >> 2;        // staging A row 0..63 (and +64)
  const int sq   = (t & 3) * 4;   // staging A k offset {0,4,8,12}
  const int wr   = t >> 4;        // staging W k row 0..15
  const int wq   = (t & 15) * 4;  // staging W col {0,4,..,60} (and +64)

  float acc[8][8];
  #pragma unroll
  for (int i = 0; i < 8; i++)
    #pragma unroll
    for (int j = 0; j < 8; j++) acc[i][j] = 0.f;

  for (int kt = 0; kt < 128; kt += 16){
    float4 a0 = make_float4(0.f,0.f,0.f,0.f), a1 = a0;
    int r0 = row0 + sr, r1 = row0 + sr + 64;
    if (r0 < n) a0 = *(const float4*)(A + (long)r0 * DD + kt + sq);
    if (r1 < n) a1 = *(const float4*)(A + (long)r1 * DD + kt + sq);
    const float4 wv0 = *(const float4*)(W + (long)(kt + wr) * DD + wq);
    const float4 wv1 = *(const float4*)(W + (long)(kt + wr) * DD + wq + 64);
    __syncthreads();
    As[sq + 0][sr]      = a0.x;  As[sq + 1][sr]      = a0.y;
    As[sq + 2][sr]      = a0.z;  As[sq + 3][sr]      = a0.w;
    As[sq + 0][sr + 64] = a1.x;  As[sq + 1][sr + 64] = a1.y;
    As[sq + 2][sr + 64] = a1.z;  As[sq + 3][sr + 64] = a1.w;
    *(float4*)(&Ws[wr][wq])      = wv0;
    *(float4*)(&Ws[wr][wq + 64]) = wv1;
    __syncthreads();
    #pragma unroll
    for (int k = 0; k < 16; k++){
      const float4 af0 = *(const float4*)(&As[k][tr * 8]);
      const float4 af1 = *(const float4*)(&As[k][tr * 8 + 4]);
      const float4 wf0 = *(const float4*)(&Ws[k][tc * 8]);
      const float4 wf1 = *(const float4*)(&Ws[k][tc * 8 + 4]);
      const float ar[8] = {af0.x,af0.y,af0.z,af0.w,af1.x,af1.y,af1.z,af1.w};
      const float wv[8] = {wf0.x,wf0.y,wf0.z,wf0.w,wf1.x,wf1.y,wf1.z,wf1.w};
      #pragma unroll
      for (int i = 0; i < 8; i++)
        #pragma unroll
        for (int j = 0; j < 8; j++)
          acc[i][j] += ar[i] * wv[j];
    }
  }
  if (BF16OUT){
    unsigned short* C = (unsigned short*)Cout;
    #pragma unroll
    for (int i = 0; i < 8; i++){
      int row = row0 + tr * 8 + i;
      if (row < n){
        uint4 pk;
        pk.x = bfpack(acc[i][0], acc[i][1]);
        pk.y = bfpack(acc[i][2], acc[i][3]);
        pk.z = bfpack(acc[i][4], acc[i][5]);
        pk.w = bfpack(acc[i][6], acc[i][7]);
        *(uint4*)(C + (long)row * DD + tc * 8) = pk;
      }
    }
  } else {
    float* C = (float*)Cout;
    #pragma unroll
    for (int i = 0; i < 8; i++){
      int row = row0 + tr * 8 + i;
      if (row < n){
        *(float4*)(C + (long)row * DD + tc * 8)     = make_float4(acc[i][0], acc[i][1], acc[i][2], acc[i][3]);
        *(float4*)(C + (long)row * DD + tc * 8 + 4) = make_float4(acc[i][4], acc[i][5], acc[i][6], acc[i][7]);
      }
    }
  }
}

// ---------- pool agg (fp32 payload, int2-packed edges) ----------
__global__ __launch_bounds__(256) void k_agg_csr(const float* __restrict__ xw,
    const int* __restrict__ rptr, const int2* __restrict__ ewk,
    const float* __restrict__ dinv, const float* __restrict__ b,
    float* __restrict__ out, int n){
  int row = blockIdx.x * 4 + (threadIdx.x >> 6);
  if (row >= n) return;
  int c = (threadIdx.x & 63) * 2;
  int j0 = __builtin_amdgcn_readfirstlane(rptr[row]);
  int j1 = __builtin_amdgcn_readfirstlane(rptr[row + 1]);
  float ax[4], ay[4];
  #pragma unroll
  for (int i = 0; i < 4; i++){ ax[i] = 0.f; ay[i] = 0.f; }
  int j = j0;
  for (; j + 3 < j1; j += 4){
    #pragma unroll
    for (int i = 0; i < 4; i++){
      int2 q = ewk[j + i];
      float w = __int_as_float(q.y);
      float2 v = *(const float2*)(xw + (long)q.x * DD + c);
      ax[i] += v.x * w; ay[i] += v.y * w;
    }
  }
  for (; j < j1; j++){
    int2 q = ewk[j];
    float w = __int_as_float(q.y);
    float2 v = *(const float2*)(xw + (long)q.x * DD + c);
    ax[0] += v.x * w; ay[0] += v.y * w;
  }
  float sax = (ax[0]+ax[1]) + (ax[2]+ax[3]);
  float say = (ay[0]+ay[1]) + (ay[2]+ay[3]);
  float dd = dinv[row];
  float2 sv = *(const float2*)(xw + (long)row * DD + c);
  float2 bb = *(const float2*)(b + c);
  float vx = sax * dd + sv.x * dd * dd + bb.x;
  float vy = say * dd + sv.y * dd * dd + bb.y;
  vx = vx > 0.f ? vx : expm1f(vx);
  vy = vy > 0.f ? vy : expm1f(vy);
  *(float2*)(out + (long)row * DD + c) = make_float2(vx, vy);
}

// ---------- conv2 agg (bf16 payload, int4-packed edges), unroll x8 ----------
__global__ __launch_bounds__(256) void k_agg_csr_b(const unsigned short* __restrict__ xwb,
    const int* __restrict__ rptr, const int4* __restrict__ ewk,
    const float* __restrict__ dinv, const float* __restrict__ b,
    float* __restrict__ out, int n){
  int row = blockIdx.x * 4 + (threadIdx.x >> 6);
  if (row >= n) return;
  int c = (threadIdx.x & 63) * 2;
  int j0 = __builtin_amdgcn_readfirstlane(rptr[row]);
  int j1 = __builtin_amdgcn_readfirstlane(rptr[row + 1]);
  float ax[8], ay[8];
  #pragma unroll
  for (int i = 0; i < 8; i++){ ax[i] = 0.f; ay[i] = 0.f; }
  int j = j0;
  for (; j + 7 < j1; j += 8){
    #pragma unroll
    for (int i = 0; i < 8; i++){
      int4 q = ewk[j + i];
      float w = __int_as_float(q.z);
      unsigned v = *(const unsigned*)(xwb + (long)q.x * DD + c);
      ax[i] += __uint_as_float(v << 16) * w;
      ay[i] += __uint_as_float(v & 0xffff0000u) * w;
    }
  }
  for (; j < j1; j++){
    int4 q = ewk[j];
    float w = __int_as_float(q.z);
    unsigned v = *(const unsigned*)(xwb + (long)q.x * DD + c);
    ax[0] += __uint_as_float(v << 16) * w;
    ay[0] += __uint_as_float(v & 0xffff0000u) * w;
  }
  float sax = ((ax[0]+ax[1])+(ax[2]+ax[3])) + ((ax[4]+ax[5])+(ax[6]+ax[7]));
  float say = ((ay[0]+ay[1])+(ay[2]+ay[3])) + ((ay[4]+ay[5])+(ay[6]+ay[7]));
  float dd = dinv[row];
  unsigned sv = *(const unsigned*)(xwb + (long)row * DD + c);
  float sx = __uint_as_float(sv << 16), sy = __uint_as_float(sv & 0xffff0000u);
  float2 bb = *(const float2*)(b + c);
  float vx = sax * dd + sx * dd * dd + bb.x;
  float vy = say * dd + sy * dd * dd + bb.y;
  vx = vx > 0.f ? vx : expm1f(vx);
  vy = vy > 0.f ? vy : expm1f(vy);
  *(float2*)(out + (long)row * DD + c) = make_float2(vx, vy);
}

// ---------- conv1 agg (sparse input, int4-packed edges), unroll x8 ----------
__global__ __launch_bounds__(256) void k_agg_csr_sp(const float* __restrict__ hw,
    const int* __restrict__ inv, const int* __restrict__ rptr,
    const int4* __restrict__ ewk,
    const float* __restrict__ dinv, const float* __restrict__ b,
    float* __restrict__ out, int n){
  int row = blockIdx.x * 4 + (threadIdx.x >> 6);
  if (row >= n) return;
  int c = (threadIdx.x & 63) * 2;
  int j0 = __builtin_amdgcn_readfirstlane(rptr[row]);
  int j1 = __builtin_amdgcn_readfirstlane(rptr[row + 1]);
  float ax[8], ay[8];
  #pragma unroll
  for (int i = 0; i < 8; i++){ ax[i] = 0.f; ay[i] = 0.f; }
  int j = j0;
  for (; j + 7 < j1; j += 8){
    #pragma unroll
    for (int i = 0; i < 8; i++){
      int4 q = ewk[j + i];
      float w = __int_as_float(q.z);
      if (q.y >= 0){
        float2 v = *(const float2*)(hw + (long)q.y * DD + c);
        ax[i] += v.x * w; ay[i] += v.y * w;
      }
    }
  }
  for (; j < j1; j++){
    int4 q = ewk[j];
    float w = __int_as_float(q.z);
    if (q.y >= 0){
      float2 v = *(const float2*)(hw + (long)q.y * DD + c);
      ax[0] += v.x * w; ay[0] += v.y * w;
    }
  }
  float sax = ((ax[0]+ax[1])+(ax[2]+ax[3])) + ((ax[4]+ax[5])+(ax[6]+ax[7]));
  float say = ((ay[0]+ay[1])+(ay[2]+ay[3])) + ((ay[4]+ay[5])+(ay[6]+ay[7]));
  float dd = dinv[row];
  int pr = inv[row];
  float sx = 0.f, sy = 0.f;
  if (pr >= 0){
    float2 sv = *(const float2*)(hw + (long)pr * DD + c);
    sx = sv.x; sy = sv.y;
  }
  float2 bb = *(const float2*)(b + c);
  float vx = sax * dd + sx * dd * dd + bb.x;
  float vy = say * dd + sy * dd * dd + bb.y;
  vx = vx > 0.f ? vx : expm1f(vx);
  vy = vy > 0.f ? vy : expm1f(vy);
  *(float2*)(out + (long)row * DD + c) = make_float2(vx, vy);
}

extern "C" void kernel_launch(void* const* d_in, const int* in_sizes, int n_in,
                              void* d_out, int out_size, void* d_ws, size_t ws_size,
                              hipStream_t stream) {
  const int*   edge   = (const int*)d_in[1];
  const float* px     = (const float*)d_in[2];
  const int*   pedge  = (const int*)d_in[3];
  const int*   unpool = (const int*)d_in[4];
  const float* W0 = (const float*)d_in[5]; const float* b0 = (const float*)d_in[6];
  const float* W1 = (const float*)d_in[7]; const float* b1 = (const float*)d_in[8];
  const float* W2 = (const float*)d_in[9]; const float* b2 = (const float*)d_in[10];
  const int n_full = in_sizes[0] / DD;
  const int E_full = in_sizes[1] / 2;
  const int n_pool = in_sizes[2] / DD;
  const int E_pool = in_sizes[3] / 2;
  float* out = (float*)d_out;

  // ---- workspace layout ----
  char* w = (char*)d_ws;
  size_t off = 0;
  auto alloc = [&](size_t bytes) -> void* {
    void* p = (void*)(w + off);
    off += (bytes + 255) / 256 * 256;
    return p;
  };
  float* dinv_p = (float*)alloc((size_t)n_pool * 4);
  float* dinv_f = (float*)alloc((size_t)n_full * 4);
  int* cnt_p  = (int*)alloc((size_t)n_pool * 4);
  int* cnt_f  = (int*)alloc((size_t)n_full * 4);
  size_t cnt_span = (size_t)((char*)(cnt_f + n_full) - (char*)cnt_p);
  int* rptr_p = (int*)alloc((size_t)(n_pool + 1) * 4);
  int* rptr_f = (int*)alloc((size_t)(n_full + 1) * 4);
  int2* ewk_p = (int2*)alloc((size_t)E_pool * 8);
  int4* ewk_f = (int4*)alloc((size_t)E_full * 16);
  int* invm   = (int*)alloc((size_t)n_full * 4);
  const int nbf = cdiv(n_full, 1024), nbp = cdiv(n_pool, 1024);
  int* bsum_f = (int*)alloc((size_t)nbf * 4);
  int* bsum_p = (int*)alloc((size_t)nbp * 4);
  const size_t big = (size_t)n_full * DD * 4;
  float* bufA = (float*)alloc(big);
  float* bufB = (float*)alloc(big);

  const int* src_f = edge;          const int* dst_f = edge + E_full;
  const int* src_p = pedge;         const int* dst_p = pedge + E_pool;

  // ---- CSR build (both graphs) + inverse unpool map ----
  (void)hipMemsetAsync(cnt_p, 0, cnt_span, stream);
  (void)hipMemsetAsync(invm, 0xFF, (size_t)n_full * 4, stream);   // -1
  k_count2<<<cdiv((long)E_full + E_pool,256),256,0,stream>>>(dst_f, E_full, cnt_f, dst_p, E_pool, cnt_p);
  const int nbi = cdiv(n_pool, 256);
  k_bsum<<<nbf + nbp + nbi,256,0,stream>>>(cnt_f, n_full, cnt_p, n_pool, bsum_f, bsum_p,
                                           nbf, nbp, unpool, invm, n_pool);
  k_scan_b<<<1,128,0,stream>>>(bsum_f, nbf, bsum_p, nbp);
  k_scan_f<<<nbf + nbp,256,0,stream>>>(cnt_f, n_full, bsum_f, cnt_p, n_pool, bsum_p,
                                       rptr_f, cnt_f, dinv_f, rptr_p, cnt_p, dinv_p,
                                       nbf, E_full, E_pool);
  k_fill2<<<cdiv((long)E_full + E_pool,256),256,0,stream>>>(
      src_f, dst_f, E_full, cnt_f, ewk_f, dinv_f, invm,
      src_p, dst_p, E_pool, cnt_p, ewk_p, dinv_p);

  float* xw0 = bufA;                      // pool rows fp32
  float* h0  = bufB;                      // pool rows fp32
  float* hw1 = bufA;                      // pool rows fp32 (xw0 dead)
  float* y1  = bufB;                      // full rows fp32 (h0 dead after gemm)
  unsigned short* xw2b = (unsigned short*)bufA;  // full rows bf16 (hw1 dead)

  // conv0 (pooled graph)
  k_gemm_t<false><<<cdiv(n_pool,128),256,0,stream>>>(px, W0, xw0, n_pool);
  k_agg_csr<<<cdiv(n_pool,4),256,0,stream>>>(xw0, rptr_p, ewk_p, dinv_p, b0, h0, n_pool);

  // conv1 (full graph, sparse input)
  k_gemm_t<false><<<cdiv(n_pool,128),256,0,stream>>>(h0, W1, hw1, n_pool);
  k_agg_csr_sp<<<cdiv(n_full,4),256,0,stream>>>(hw1, invm, rptr_f, ewk_f, dinv_f, b1, y1, n_full);

  // conv2 (full graph, bf16 gather payload)
  k_gemm_t<true><<<cdiv(n_full,128),256,0,stream>>>(y1, W2, xw2b, n_full);
  k_agg_csr_b<<<cdiv(n_full,4),256,0,stream>>>(xw2b, rptr_f, ewk_f, dinv_f, b2, out, n_full);
}

// Round 10
// 299.569 us; speedup vs baseline: 1.0824x; 1.0824x over previous
//
#include <hip/hip_runtime.h>
#include <math.h>

#define DD 128

static inline int cdiv(long a, long b){ return (int)((a + b - 1) / b); }

__device__ __forceinline__ unsigned bfpack(float a, float b){
  unsigned ua = __float_as_uint(a), ub = __float_as_uint(b);
  ua = (ua + 0x7fffu + ((ua >> 16) & 1u)) >> 16;
  ub = (ub + 0x7fffu + ((ub >> 16) & 1u)) >> 16;
  return ua | (ub << 16);
}

// ---------- degree count + edge rank (both graphs, one launch) ----------
__global__ void k_count2(const int* __restrict__ dst_f, int Ef, int* __restrict__ cnt_f,
                         int* __restrict__ rank_f,
                         const int* __restrict__ dst_p, int Ep, int* __restrict__ cnt_p,
                         int* __restrict__ rank_p){
  int e = blockIdx.x * blockDim.x + threadIdx.x;
  if (e < Ef) rank_f[e] = atomicAdd(&cnt_f[dst_f[e]], 1);
  else { e -= Ef; if (e < Ep) rank_p[e] = atomicAdd(&cnt_p[dst_p[e]], 1); }
}

// ---------- hierarchical scan phase 1 + inv scatter (fused) ----------
__global__ __launch_bounds__(256) void k_bsum(
    const int* __restrict__ cnt_f, int nf, const int* __restrict__ cnt_p, int np,
    int* __restrict__ bsum_f, int* __restrict__ bsum_p, int nbf, int nbp,
    const int* __restrict__ unpool, int* __restrict__ inv, int npool){
  int bi = blockIdx.x;
  if (bi >= nbf + nbp){
    int i = (bi - nbf - nbp) * 256 + threadIdx.x;
    if (i < npool) inv[unpool[i]] = i;
    return;
  }
  const int* cnt; int n; int* bsum; int b;
  if (bi < nbf){ cnt = cnt_f; n = nf; bsum = bsum_f; b = bi; }
  else         { cnt = cnt_p; n = np; bsum = bsum_p; b = bi - nbf; }
  __shared__ int s[256];
  int t = threadIdx.x;
  long base = (long)b * 1024 + t * 4;
  int v = 0;
  if (base + 3 < n){ int4 q = *(const int4*)(cnt + base); v = q.x + q.y + q.z + q.w; }
  else { for (int j = 0; j < 4; j++) if (base + j < n) v += cnt[base + j]; }
  s[t] = v; __syncthreads();
  for (int off = 128; off > 0; off >>= 1){ if (t < off) s[t] += s[t + off]; __syncthreads(); }
  if (t == 0) bsum[b] = s[0];
}

// phase 2: exclusive scan of block sums
__global__ __launch_bounds__(128) void k_scan_b(int* __restrict__ bsum_f, int nbf,
                                                int* __restrict__ bsum_p, int nbp){
  __shared__ int s[128];
  int t = threadIdx.x;
  int v = (t < nbf) ? bsum_f[t] : 0;
  s[t] = v; __syncthreads();
  for (int off = 1; off < 128; off <<= 1){ int u = (t >= off) ? s[t - off] : 0; __syncthreads(); s[t] += u; __syncthreads(); }
  if (t < nbf) bsum_f[t] = s[t] - v;
  __syncthreads();
  int v2 = (t < nbp) ? bsum_p[t] : 0;
  s[t] = v2; __syncthreads();
  for (int off = 1; off < 128; off <<= 1){ int u = (t >= off) ? s[t - off] : 0; __syncthreads(); s[t] += u; __syncthreads(); }
  if (t < nbp) bsum_p[t] = s[t] - v2;
}

// phase 3: local scan -> rptr, dinv
__global__ __launch_bounds__(256) void k_scan_f(
    const int* __restrict__ cnt_f, int nf, const int* __restrict__ bsum_f,
    const int* __restrict__ cnt_p, int np, const int* __restrict__ bsum_p,
    int* __restrict__ rptr_f, float* __restrict__ dinv_f,
    int* __restrict__ rptr_p, float* __restrict__ dinv_p,
    int nbf, int Ef, int Ep){
  const int* cnt; const int* bsum; int* rptr; float* dinv; int n; int b;
  if ((int)blockIdx.x < nbf){ cnt=cnt_f; bsum=bsum_f; rptr=rptr_f; dinv=dinv_f; n=nf; b=blockIdx.x; }
  else                      { cnt=cnt_p; bsum=bsum_p; rptr=rptr_p; dinv=dinv_p; n=np; b=blockIdx.x-nbf; }
  __shared__ int s[256];
  int t = threadIdx.x;
  long base = (long)b * 1024 + t * 4;
  int c0=0,c1=0,c2=0,c3=0;
  if (base + 3 < n){ int4 q = *(const int4*)(cnt + base); c0=q.x; c1=q.y; c2=q.z; c3=q.w; }
  else {
    if (base + 0 < n) c0 = cnt[base + 0];
    if (base + 1 < n) c1 = cnt[base + 1];
    if (base + 2 < n) c2 = cnt[base + 2];
  }
  int tsum = c0 + c1 + c2 + c3;
  s[t] = tsum; __syncthreads();
  for (int off = 1; off < 256; off <<= 1){ int u = (t >= off) ? s[t - off] : 0; __syncthreads(); s[t] += u; __syncthreads(); }
  int run = bsum[b] + s[t] - tsum;
  int r0 = run, r1 = r0 + c0, r2 = r1 + c1, r3 = r2 + c2;
  if (base + 3 < n){
    *(int4*)(rptr + base) = make_int4(r0, r1, r2, r3);
    dinv[base + 0] = rsqrtf((float)(c0 + 1));
    dinv[base + 1] = rsqrtf((float)(c1 + 1));
    dinv[base + 2] = rsqrtf((float)(c2 + 1));
    dinv[base + 3] = rsqrtf((float)(c3 + 1));
  } else {
    if (base + 0 < n){ rptr[base+0]=r0; dinv[base+0]=rsqrtf((float)(c0+1)); }
    if (base + 1 < n){ rptr[base+1]=r1; dinv[base+1]=rsqrtf((float)(c1+1)); }
    if (base + 2 < n){ rptr[base+2]=r2; dinv[base+2]=rsqrtf((float)(c2+1)); }
  }
  if (blockIdx.x == 0 && t == 0){ rptr_f[nf] = Ef; rptr_p[np] = Ep; }
}

// ---------- CSR fill: NO atomics (p = rptr[dst] + rank[e]), one packed store ----------
__global__ void k_fill2(const int* __restrict__ src_f, const int* __restrict__ dst_f, int Ef,
                        const int* __restrict__ rptr_f, const int* __restrict__ rank_f,
                        int4* __restrict__ ewk_f,
                        const float* __restrict__ dinv_f, const int* __restrict__ inv,
                        const int* __restrict__ src_p, const int* __restrict__ dst_p, int Ep,
                        const int* __restrict__ rptr_p, const int* __restrict__ rank_p,
                        int2* __restrict__ ewk_p,
                        const float* __restrict__ dinv_p){
  int e = blockIdx.x * blockDim.x + threadIdx.x;
  if (e < Ef){
    int s = src_f[e];
    int p = rptr_f[dst_f[e]] + rank_f[e];
    ewk_f[p] = make_int4(s, inv[s], __float_as_int(dinv_f[s]), 0);
  } else {
    e -= Ef;
    if (e < Ep){
      int s = src_p[e];
      int p = rptr_p[dst_p[e]] + rank_p[e];
      ewk_p[p] = make_int2(s, __float_as_int(dinv_p[s]));
    }
  }
}

// ---------- GEMM 128x128 tile, 8x8 per thread ----------
template <bool BF16OUT>
__global__ __launch_bounds__(256) void k_gemm_t(const float* __restrict__ A,
                                                const float* __restrict__ W,
                                                void* __restrict__ Cout, int n){
  __shared__ float As[16][132];
  __shared__ float Ws[16][128];
  const int t    = threadIdx.x;
  const int row0 = blockIdx.x * 128;
  const int tc   = t & 15;
  const int tr   = t >> 4;
  const int sr   = t >> 2;
  const int sq   = (t & 3) * 4;
  const int wr   = t >> 4;
  const int wq   = (t & 15) * 4;

  float acc[8][8];
  #pragma unroll
  for (int i = 0; i < 8; i++)
    #pragma unroll
    for (int j = 0; j < 8; j++) acc[i][j] = 0.f;

  for (int kt = 0; kt < 128; kt += 16){
    float4 a0 = make_float4(0.f,0.f,0.f,0.f), a1 = a0;
    int r0 = row0 + sr, r1 = row0 + sr + 64;
    if (r0 < n) a0 = *(const float4*)(A + (long)r0 * DD + kt + sq);
    if (r1 < n) a1 = *(const float4*)(A + (long)r1 * DD + kt + sq);
    const float4 wv0 = *(const float4*)(W + (long)(kt + wr) * DD + wq);
    const float4 wv1 = *(const float4*)(W + (long)(kt + wr) * DD + wq + 64);
    __syncthreads();
    As[sq + 0][sr]      = a0.x;  As[sq + 1][sr]      = a0.y;
    As[sq + 2][sr]      = a0.z;  As[sq + 3][sr]      = a0.w;
    As[sq + 0][sr + 64] = a1.x;  As[sq + 1][sr + 64] = a1.y;
    As[sq + 2][sr + 64] = a1.z;  As[sq + 3][sr + 64] = a1.w;
    *(float4*)(&Ws[wr][wq])      = wv0;
    *(float4*)(&Ws[wr][wq + 64]) = wv1;
    __syncthreads();
    #pragma unroll
    for (int k = 0; k < 16; k++){
      const float4 af0 = *(const float4*)(&As[k][tr * 8]);
      const float4 af1 = *(const float4*)(&As[k][tr * 8 + 4]);
      const float4 wf0 = *(const float4*)(&Ws[k][tc * 8]);
      const float4 wf1 = *(const float4*)(&Ws[k][tc * 8 + 4]);
      const float ar[8] = {af0.x,af0.y,af0.z,af0.w,af1.x,af1.y,af1.z,af1.w};
      const float wv[8] = {wf0.x,wf0.y,wf0.z,wf0.w,wf1.x,wf1.y,wf1.z,wf1.w};
      #pragma unroll
      for (int i = 0; i < 8; i++)
        #pragma unroll
        for (int j = 0; j < 8; j++)
          acc[i][j] += ar[i] * wv[j];
    }
  }
  if (BF16OUT){
    unsigned short* C = (unsigned short*)Cout;
    #pragma unroll
    for (int i = 0; i < 8; i++){
      int row = row0 + tr * 8 + i;
      if (row < n){
        uint4 pk;
        pk.x = bfpack(acc[i][0], acc[i][1]);
        pk.y = bfpack(acc[i][2], acc[i][3]);
        pk.z = bfpack(acc[i][4], acc[i][5]);
        pk.w = bfpack(acc[i][6], acc[i][7]);
        *(uint4*)(C + (long)row * DD + tc * 8) = pk;
      }
    }
  } else {
    float* C = (float*)Cout;
    #pragma unroll
    for (int i = 0; i < 8; i++){
      int row = row0 + tr * 8 + i;
      if (row < n){
        *(float4*)(C + (long)row * DD + tc * 8)     = make_float4(acc[i][0], acc[i][1], acc[i][2], acc[i][3]);
        *(float4*)(C + (long)row * DD + tc * 8 + 4) = make_float4(acc[i][4], acc[i][5], acc[i][6], acc[i][7]);
      }
    }
  }
}

// ---------- pool agg (fp32 payload, int2-packed edges) ----------
__global__ __launch_bounds__(256) void k_agg_csr(const float* __restrict__ xw,
    const int* __restrict__ rptr, const int2* __restrict__ ewk,
    const float* __restrict__ dinv, const float* __restrict__ b,
    float* __restrict__ out, int n){
  int row = blockIdx.x * 4 + (threadIdx.x >> 6);
  if (row >= n) return;
  int c = (threadIdx.x & 63) * 2;
  int j0 = __builtin_amdgcn_readfirstlane(rptr[row]);
  int j1 = __builtin_amdgcn_readfirstlane(rptr[row + 1]);
  float ax[4], ay[4];
  #pragma unroll
  for (int i = 0; i < 4; i++){ ax[i] = 0.f; ay[i] = 0.f; }
  int j = j0;
  for (; j + 3 < j1; j += 4){
    #pragma unroll
    for (int i = 0; i < 4; i++){
      int2 q = ewk[j + i];
      float w = __int_as_float(q.y);
      float2 v = *(const float2*)(xw + (long)q.x * DD + c);
      ax[i] += v.x * w; ay[i] += v.y * w;
    }
  }
  for (; j < j1; j++){
    int2 q = ewk[j];
    float w = __int_as_float(q.y);
    float2 v = *(const float2*)(xw + (long)q.x * DD + c);
    ax[0] += v.x * w; ay[0] += v.y * w;
  }
  float sax = (ax[0]+ax[1]) + (ax[2]+ax[3]);
  float say = (ay[0]+ay[1]) + (ay[2]+ay[3]);
  float dd = dinv[row];
  float2 sv = *(const float2*)(xw + (long)row * DD + c);
  float2 bb = *(const float2*)(b + c);
  float vx = sax * dd + sv.x * dd * dd + bb.x;
  float vy = say * dd + sv.y * dd * dd + bb.y;
  vx = vx > 0.f ? vx : expm1f(vx);
  vy = vy > 0.f ? vy : expm1f(vy);
  *(float2*)(out + (long)row * DD + c) = make_float2(vx, vy);
}

// ---------- conv2 agg (bf16 payload, int4-packed edges), unroll x8 ----------
__global__ __launch_bounds__(256) void k_agg_csr_b(const unsigned short* __restrict__ xwb,
    const int* __restrict__ rptr, const int4* __restrict__ ewk,
    const float* __restrict__ dinv, const float* __restrict__ b,
    float* __restrict__ out, int n){
  int row = blockIdx.x * 4 + (threadIdx.x >> 6);
  if (row >= n) return;
  int c = (threadIdx.x & 63) * 2;
  int j0 = __builtin_amdgcn_readfirstlane(rptr[row]);
  int j1 = __builtin_amdgcn_readfirstlane(rptr[row + 1]);
  float ax[8], ay[8];
  #pragma unroll
  for (int i = 0; i < 8; i++){ ax[i] = 0.f; ay[i] = 0.f; }
  int j = j0;
  for (; j + 7 < j1; j += 8){
    #pragma unroll
    for (int i = 0; i < 8; i++){
      int4 q = ewk[j + i];
      float w = __int_as_float(q.z);
      unsigned v = *(const unsigned*)(xwb + (long)q.x * DD + c);
      ax[i] += __uint_as_float(v << 16) * w;
      ay[i] += __uint_as_float(v & 0xffff0000u) * w;
    }
  }
  for (; j < j1; j++){
    int4 q = ewk[j];
    float w = __int_as_float(q.z);
    unsigned v = *(const unsigned*)(xwb + (long)q.x * DD + c);
    ax[0] += __uint_as_float(v << 16) * w;
    ay[0] += __uint_as_float(v & 0xffff0000u) * w;
  }
  float sax = ((ax[0]+ax[1])+(ax[2]+ax[3])) + ((ax[4]+ax[5])+(ax[6]+ax[7]));
  float say = ((ay[0]+ay[1])+(ay[2]+ay[3])) + ((ay[4]+ay[5])+(ay[6]+ay[7]));
  float dd = dinv[row];
  unsigned sv = *(const unsigned*)(xwb + (long)row * DD + c);
  float sx = __uint_as_float(sv << 16), sy = __uint_as_float(sv & 0xffff0000u);
  float2 bb = *(const float2*)(b + c);
  float vx = sax * dd + sx * dd * dd + bb.x;
  float vy = say * dd + sy * dd * dd + bb.y;
  vx = vx > 0.f ? vx : expm1f(vx);
  vy = vy > 0.f ? vy : expm1f(vy);
  *(float2*)(out + (long)row * DD + c) = make_float2(vx, vy);
}

// ---------- conv1 agg (sparse input, int4-packed edges), unroll x8 ----------
__global__ __launch_bounds__(256) void k_agg_csr_sp(const float* __restrict__ hw,
    const int* __restrict__ inv, const int* __restrict__ rptr,
    const int4* __restrict__ ewk,
    const float* __restrict__ dinv, const float* __restrict__ b,
    float* __restrict__ out, int n){
  int row = blockIdx.x * 4 + (threadIdx.x >> 6);
  if (row >= n) return;
  int c = (threadIdx.x & 63) * 2;
  int j0 = __builtin_amdgcn_readfirstlane(rptr[row]);
  int j1 = __builtin_amdgcn_readfirstlane(rptr[row + 1]);
  float ax[8], ay[8];
  #pragma unroll
  for (int i = 0; i < 8; i++){ ax[i] = 0.f; ay[i] = 0.f; }
  int j = j0;
  for (; j + 7 < j1; j += 8){
    #pragma unroll
    for (int i = 0; i < 8; i++){
      int4 q = ewk[j + i];
      float w = __int_as_float(q.z);
      if (q.y >= 0){
        float2 v = *(const float2*)(hw + (long)q.y * DD + c);
        ax[i] += v.x * w; ay[i] += v.y * w;
      }
    }
  }
  for (; j < j1; j++){
    int4 q = ewk[j];
    float w = __int_as_float(q.z);
    if (q.y >= 0){
      float2 v = *(const float2*)(hw + (long)q.y * DD + c);
      ax[0] += v.x * w; ay[0] += v.y * w;
    }
  }
  float sax = ((ax[0]+ax[1])+(ax[2]+ax[3])) + ((ax[4]+ax[5])+(ax[6]+ax[7]));
  float say = ((ay[0]+ay[1])+(ay[2]+ay[3])) + ((ay[4]+ay[5])+(ay[6]+ay[7]));
  float dd = dinv[row];
  int pr = inv[row];
  float sx = 0.f, sy = 0.f;
  if (pr >= 0){
    float2 sv = *(const float2*)(hw + (long)pr * DD + c);
    sx = sv.x; sy = sv.y;
  }
  float2 bb = *(const float2*)(b + c);
  float vx = sax * dd + sx * dd * dd + bb.x;
  float vy = say * dd + sy * dd * dd + bb.y;
  vx = vx > 0.f ? vx : expm1f(vx);
  vy = vy > 0.f ? vy : expm1f(vy);
  *(float2*)(out + (long)row * DD + c) = make_float2(vx, vy);
}

extern "C" void kernel_launch(void* const* d_in, const int* in_sizes, int n_in,
                              void* d_out, int out_size, void* d_ws, size_t ws_size,
                              hipStream_t stream) {
  const int*   edge   = (const int*)d_in[1];
  const float* px     = (const float*)d_in[2];
  const int*   pedge  = (const int*)d_in[3];
  const int*   unpool = (const int*)d_in[4];
  const float* W0 = (const float*)d_in[5]; const float* b0 = (const float*)d_in[6];
  const float* W1 = (const float*)d_in[7]; const float* b1 = (const float*)d_in[8];
  const float* W2 = (const float*)d_in[9]; const float* b2 = (const float*)d_in[10];
  const int n_full = in_sizes[0] / DD;
  const int E_full = in_sizes[1] / 2;
  const int n_pool = in_sizes[2] / DD;
  const int E_pool = in_sizes[3] / 2;
  float* out = (float*)d_out;

  // ---- workspace layout ----
  char* w = (char*)d_ws;
  size_t off = 0;
  auto alloc = [&](size_t bytes) -> void* {
    void* p = (void*)(w + off);
    off += (bytes + 255) / 256 * 256;
    return p;
  };
  float* dinv_p = (float*)alloc((size_t)n_pool * 4);
  float* dinv_f = (float*)alloc((size_t)n_full * 4);
  int* cnt_p  = (int*)alloc((size_t)n_pool * 4);
  int* cnt_f  = (int*)alloc((size_t)n_full * 4);
  size_t cnt_span = (size_t)((char*)(cnt_f + n_full) - (char*)cnt_p);
  int* rptr_p = (int*)alloc((size_t)(n_pool + 1) * 4);
  int* rptr_f = (int*)alloc((size_t)(n_full + 1) * 4);
  int* rank_p = (int*)alloc((size_t)E_pool * 4);
  int* rank_f = (int*)alloc((size_t)E_full * 4);
  int2* ewk_p = (int2*)alloc((size_t)E_pool * 8);
  int4* ewk_f = (int4*)alloc((size_t)E_full * 16);
  int* invm   = (int*)alloc((size_t)n_full * 4);
  const int nbf = cdiv(n_full, 1024), nbp = cdiv(n_pool, 1024);
  int* bsum_f = (int*)alloc((size_t)nbf * 4);
  int* bsum_p = (int*)alloc((size_t)nbp * 4);
  const size_t big = (size_t)n_full * DD * 4;
  float* bufA = (float*)alloc(big);
  float* bufB = (float*)alloc(big);

  const int* src_f = edge;          const int* dst_f = edge + E_full;
  const int* src_p = pedge;         const int* dst_p = pedge + E_pool;

  // ---- CSR build (both graphs) + inverse unpool map ----
  (void)hipMemsetAsync(cnt_p, 0, cnt_span, stream);
  (void)hipMemsetAsync(invm, 0xFF, (size_t)n_full * 4, stream);   // -1
  k_count2<<<cdiv((long)E_full + E_pool,256),256,0,stream>>>(dst_f, E_full, cnt_f, rank_f,
                                                             dst_p, E_pool, cnt_p, rank_p);
  const int nbi = cdiv(n_pool, 256);
  k_bsum<<<nbf + nbp + nbi,256,0,stream>>>(cnt_f, n_full, cnt_p, n_pool, bsum_f, bsum_p,
                                           nbf, nbp, unpool, invm, n_pool);
  k_scan_b<<<1,128,0,stream>>>(bsum_f, nbf, bsum_p, nbp);
  k_scan_f<<<nbf + nbp,256,0,stream>>>(cnt_f, n_full, bsum_f, cnt_p, n_pool, bsum_p,
                                       rptr_f, dinv_f, rptr_p, dinv_p,
                                       nbf, E_full, E_pool);
  k_fill2<<<cdiv((long)E_full + E_pool,256),256,0,stream>>>(
      src_f, dst_f, E_full, rptr_f, rank_f, ewk_f, dinv_f, invm,
      src_p, dst_p, E_pool, rptr_p, rank_p, ewk_p, dinv_p);

  float* xw0 = bufA;                      // pool rows fp32
  float* h0  = bufB;                      // pool rows fp32
  float* hw1 = bufA;                      // pool rows fp32 (xw0 dead)
  float* y1  = bufB;                      // full rows fp32 (h0 dead after gemm)
  unsigned short* xw2b = (unsigned short*)bufA;  // full rows bf16 (hw1 dead)

  // conv0 (pooled graph)
  k_gemm_t<false><<<cdiv(n_pool,128),256,0,stream>>>(px, W0, xw0, n_pool);
  k_agg_csr<<<cdiv(n_pool,4),256,0,stream>>>(xw0, rptr_p, ewk_p, dinv_p, b0, h0, n_pool);

  // conv1 (full graph, sparse input)
  k_gemm_t<false><<<cdiv(n_pool,128),256,0,stream>>>(h0, W1, hw1, n_pool);
  k_agg_csr_sp<<<cdiv(n_full,4),256,0,stream>>>(hw1, invm, rptr_f, ewk_f, dinv_f, b1, y1, n_full);

  // conv2 (full graph, bf16 gather payload)
  k_gemm_t<true><<<cdiv(n_full,128),256,0,stream>>>(y1, W2, xw2b, n_full);
  k_agg_csr_b<<<cdiv(n_full,4),256,0,stream>>>(xw2b, rptr_f, ewk_f, dinv_f, b2, out, n_full);
}

// Round 11
// 296.512 us; speedup vs baseline: 1.0935x; 1.0103x over previous
//
#include <hip/hip_runtime.h>
#include <math.h>

#define DD 128

static inline int cdiv(long a, long b){ return (int)((a + b - 1) / b); }

__device__ __forceinline__ unsigned bfpack(float a, float b){
  unsigned ua = __float_as_uint(a), ub = __float_as_uint(b);
  ua = (ua + 0x7fffu + ((ua >> 16) & 1u)) >> 16;
  ub = (ub + 0x7fffu + ((ub >> 16) & 1u)) >> 16;
  return ua | (ub << 16);
}

// ---------- degree count + edge rank (both graphs) + invm=-1 init, one launch ----------
__global__ void k_count2(const int* __restrict__ dst_f, int Ef, int* __restrict__ cnt_f,
                         int* __restrict__ rank_f,
                         const int* __restrict__ dst_p, int Ep, int* __restrict__ cnt_p,
                         int* __restrict__ rank_p,
                         int* __restrict__ invm, int nf){
  int e = blockIdx.x * blockDim.x + threadIdx.x;
  if (e < Ef){ rank_f[e] = atomicAdd(&cnt_f[dst_f[e]], 1); return; }
  e -= Ef;
  if (e < Ep){ rank_p[e] = atomicAdd(&cnt_p[dst_p[e]], 1); return; }
  e -= Ep;
  if (e < nf) invm[e] = -1;
}

// ---------- hierarchical scan phase 1 + inv scatter (fused) ----------
__global__ __launch_bounds__(256) void k_bsum(
    const int* __restrict__ cnt_f, int nf, const int* __restrict__ cnt_p, int np,
    int* __restrict__ bsum_f, int* __restrict__ bsum_p, int nbf, int nbp,
    const int* __restrict__ unpool, int* __restrict__ inv, int npool){
  int bi = blockIdx.x;
  if (bi >= nbf + nbp){
    int i = (bi - nbf - nbp) * 256 + threadIdx.x;
    if (i < npool) inv[unpool[i]] = i;
    return;
  }
  const int* cnt; int n; int* bsum; int b;
  if (bi < nbf){ cnt = cnt_f; n = nf; bsum = bsum_f; b = bi; }
  else         { cnt = cnt_p; n = np; bsum = bsum_p; b = bi - nbf; }
  __shared__ int s[256];
  int t = threadIdx.x;
  long base = (long)b * 1024 + t * 4;
  int v = 0;
  if (base + 3 < n){ int4 q = *(const int4*)(cnt + base); v = q.x + q.y + q.z + q.w; }
  else { for (int j = 0; j < 4; j++) if (base + j < n) v += cnt[base + j]; }
  s[t] = v; __syncthreads();
  for (int off = 128; off > 0; off >>= 1){ if (t < off) s[t] += s[t + off]; __syncthreads(); }
  if (t == 0) bsum[b] = s[0];
}

// phase 2: exclusive scan of block sums
__global__ __launch_bounds__(128) void k_scan_b(int* __restrict__ bsum_f, int nbf,
                                                int* __restrict__ bsum_p, int nbp){
  __shared__ int s[128];
  int t = threadIdx.x;
  int v = (t < nbf) ? bsum_f[t] : 0;
  s[t] = v; __syncthreads();
  for (int off = 1; off < 128; off <<= 1){ int u = (t >= off) ? s[t - off] : 0; __syncthreads(); s[t] += u; __syncthreads(); }
  if (t < nbf) bsum_f[t] = s[t] - v;
  __syncthreads();
  int v2 = (t < nbp) ? bsum_p[t] : 0;
  s[t] = v2; __syncthreads();
  for (int off = 1; off < 128; off <<= 1){ int u = (t >= off) ? s[t - off] : 0; __syncthreads(); s[t] += u; __syncthreads(); }
  if (t < nbp) bsum_p[t] = s[t] - v2;
}

// phase 3: local scan -> rptr, dinv
__global__ __launch_bounds__(256) void k_scan_f(
    const int* __restrict__ cnt_f, int nf, const int* __restrict__ bsum_f,
    const int* __restrict__ cnt_p, int np, const int* __restrict__ bsum_p,
    int* __restrict__ rptr_f, float* __restrict__ dinv_f,
    int* __restrict__ rptr_p, float* __restrict__ dinv_p,
    int nbf, int Ef, int Ep){
  const int* cnt; const int* bsum; int* rptr; float* dinv; int n; int b;
  if ((int)blockIdx.x < nbf){ cnt=cnt_f; bsum=bsum_f; rptr=rptr_f; dinv=dinv_f; n=nf; b=blockIdx.x; }
  else                      { cnt=cnt_p; bsum=bsum_p; rptr=rptr_p; dinv=dinv_p; n=np; b=blockIdx.x-nbf; }
  __shared__ int s[256];
  int t = threadIdx.x;
  long base = (long)b * 1024 + t * 4;
  int c0=0,c1=0,c2=0,c3=0;
  if (base + 3 < n){ int4 q = *(const int4*)(cnt + base); c0=q.x; c1=q.y; c2=q.z; c3=q.w; }
  else {
    if (base + 0 < n) c0 = cnt[base + 0];
    if (base + 1 < n) c1 = cnt[base + 1];
    if (base + 2 < n) c2 = cnt[base + 2];
  }
  int tsum = c0 + c1 + c2 + c3;
  s[t] = tsum; __syncthreads();
  for (int off = 1; off < 256; off <<= 1){ int u = (t >= off) ? s[t - off] : 0; __syncthreads(); s[t] += u; __syncthreads(); }
  int run = bsum[b] + s[t] - tsum;
  int r0 = run, r1 = r0 + c0, r2 = r1 + c1, r3 = r2 + c2;
  if (base + 3 < n){
    *(int4*)(rptr + base) = make_int4(r0, r1, r2, r3);
    dinv[base + 0] = rsqrtf((float)(c0 + 1));
    dinv[base + 1] = rsqrtf((float)(c1 + 1));
    dinv[base + 2] = rsqrtf((float)(c2 + 1));
    dinv[base + 3] = rsqrtf((float)(c3 + 1));
  } else {
    if (base + 0 < n){ rptr[base+0]=r0; dinv[base+0]=rsqrtf((float)(c0+1)); }
    if (base + 1 < n){ rptr[base+1]=r1; dinv[base+1]=rsqrtf((float)(c1+1)); }
    if (base + 2 < n){ rptr[base+2]=r2; dinv[base+2]=rsqrtf((float)(c2+1)); }
  }
  if (blockIdx.x == 0 && t == 0){ rptr_f[nf] = Ef; rptr_p[np] = Ep; }
}

// ---------- CSR fill: NO atomics (p = rptr[dst] + rank[e]), one packed store ----------
__global__ void k_fill2(const int* __restrict__ src_f, const int* __restrict__ dst_f, int Ef,
                        const int* __restrict__ rptr_f, const int* __restrict__ rank_f,
                        int4* __restrict__ ewk_f,
                        const float* __restrict__ dinv_f, const int* __restrict__ inv,
                        const int* __restrict__ src_p, const int* __restrict__ dst_p, int Ep,
                        const int* __restrict__ rptr_p, const int* __restrict__ rank_p,
                        int2* __restrict__ ewk_p,
                        const float* __restrict__ dinv_p){
  int e = blockIdx.x * blockDim.x + threadIdx.x;
  if (e < Ef){
    int s = src_f[e];
    int p = rptr_f[dst_f[e]] + rank_f[e];
    ewk_f[p] = make_int4(s, inv[s], __float_as_int(dinv_f[s]), 0);
  } else {
    e -= Ef;
    if (e < Ep){
      int s = src_p[e];
      int p = rptr_p[dst_p[e]] + rank_p[e];
      ewk_p[p] = make_int2(s, __float_as_int(dinv_p[s]));
    }
  }
}

// ---------- GEMM 128x128 tile, 8x8 per thread ----------
template <bool BF16OUT>
__global__ __launch_bounds__(256) void k_gemm_t(const float* __restrict__ A,
                                                const float* __restrict__ W,
                                                void* __restrict__ Cout, int n){
  __shared__ float As[16][132];
  __shared__ float Ws[16][128];
  const int t    = threadIdx.x;
  const int row0 = blockIdx.x * 128;
  const int tc   = t & 15;
  const int tr   = t >> 4;
  const int sr   = t >> 2;
  const int sq   = (t & 3) * 4;
  const int wr   = t >> 4;
  const int wq   = (t & 15) * 4;

  float acc[8][8];
  #pragma unroll
  for (int i = 0; i < 8; i++)
    #pragma unroll
    for (int j = 0; j < 8; j++) acc[i][j] = 0.f;

  for (int kt = 0; kt < 128; kt += 16){
    float4 a0 = make_float4(0.f,0.f,0.f,0.f), a1 = a0;
    int r0 = row0 + sr, r1 = row0 + sr + 64;
    if (r0 < n) a0 = *(const float4*)(A + (long)r0 * DD + kt + sq);
    if (r1 < n) a1 = *(const float4*)(A + (long)r1 * DD + kt + sq);
    const float4 wv0 = *(const float4*)(W + (long)(kt + wr) * DD + wq);
    const float4 wv1 = *(const float4*)(W + (long)(kt + wr) * DD + wq + 64);
    __syncthreads();
    As[sq + 0][sr]      = a0.x;  As[sq + 1][sr]      = a0.y;
    As[sq + 2][sr]      = a0.z;  As[sq + 3][sr]      = a0.w;
    As[sq + 0][sr + 64] = a1.x;  As[sq + 1][sr + 64] = a1.y;
    As[sq + 2][sr + 64] = a1.z;  As[sq + 3][sr + 64] = a1.w;
    *(float4*)(&Ws[wr][wq])      = wv0;
    *(float4*)(&Ws[wr][wq + 64]) = wv1;
    __syncthreads();
    #pragma unroll
    for (int k = 0; k < 16; k++){
      const float4 af0 = *(const float4*)(&As[k][tr * 8]);
      const float4 af1 = *(const float4*)(&As[k][tr * 8 + 4]);
      const float4 wf0 = *(const float4*)(&Ws[k][tc * 8]);
      const float4 wf1 = *(const float4*)(&Ws[k][tc * 8 + 4]);
      const float ar[8] = {af0.x,af0.y,af0.z,af0.w,af1.x,af1.y,af1.z,af1.w};
      const float wv[8] = {wf0.x,wf0.y,wf0.z,wf0.w,wf1.x,wf1.y,wf1.z,wf1.w};
      #pragma unroll
      for (int i = 0; i < 8; i++)
        #pragma unroll
        for (int j = 0; j < 8; j++)
          acc[i][j] += ar[i] * wv[j];
    }
  }
  if (BF16OUT){
    unsigned short* C = (unsigned short*)Cout;
    #pragma unroll
    for (int i = 0; i < 8; i++){
      int row = row0 + tr * 8 + i;
      if (row < n){
        uint4 pk;
        pk.x = bfpack(acc[i][0], acc[i][1]);
        pk.y = bfpack(acc[i][2], acc[i][3]);
        pk.z = bfpack(acc[i][4], acc[i][5]);
        pk.w = bfpack(acc[i][6], acc[i][7]);
        *(uint4*)(C + (long)row * DD + tc * 8) = pk;
      }
    }
  } else {
    float* C = (float*)Cout;
    #pragma unroll
    for (int i = 0; i < 8; i++){
      int row = row0 + tr * 8 + i;
      if (row < n){
        *(float4*)(C + (long)row * DD + tc * 8)     = make_float4(acc[i][0], acc[i][1], acc[i][2], acc[i][3]);
        *(float4*)(C + (long)row * DD + tc * 8 + 4) = make_float4(acc[i][4], acc[i][5], acc[i][6], acc[i][7]);
      }
    }
  }
}

// ---------- pool agg (fp32 payload, int2-packed edges) ----------
__global__ __launch_bounds__(256) void k_agg_csr(const float* __restrict__ xw,
    const int* __restrict__ rptr, const int2* __restrict__ ewk,
    const float* __restrict__ dinv, const float* __restrict__ b,
    float* __restrict__ out, int n){
  int row = blockIdx.x * 4 + (threadIdx.x >> 6);
  if (row >= n) return;
  int c = (threadIdx.x & 63) * 2;
  int j0 = __builtin_amdgcn_readfirstlane(rptr[row]);
  int j1 = __builtin_amdgcn_readfirstlane(rptr[row + 1]);
  float ax[4], ay[4];
  #pragma unroll
  for (int i = 0; i < 4; i++){ ax[i] = 0.f; ay[i] = 0.f; }
  int j = j0;
  for (; j + 3 < j1; j += 4){
    #pragma unroll
    for (int i = 0; i < 4; i++){
      int2 q = ewk[j + i];
      float w = __int_as_float(q.y);
      float2 v = *(const float2*)(xw + (long)q.x * DD + c);
      ax[i] += v.x * w; ay[i] += v.y * w;
    }
  }
  for (; j < j1; j++){
    int2 q = ewk[j];
    float w = __int_as_float(q.y);
    float2 v = *(const float2*)(xw + (long)q.x * DD + c);
    ax[0] += v.x * w; ay[0] += v.y * w;
  }
  float sax = (ax[0]+ax[1]) + (ax[2]+ax[3]);
  float say = (ay[0]+ay[1]) + (ay[2]+ay[3]);
  float dd = dinv[row];
  float2 sv = *(const float2*)(xw + (long)row * DD + c);
  float2 bb = *(const float2*)(b + c);
  float vx = sax * dd + sv.x * dd * dd + bb.x;
  float vy = say * dd + sv.y * dd * dd + bb.y;
  vx = vx > 0.f ? vx : expm1f(vx);
  vy = vy > 0.f ? vy : expm1f(vy);
  *(float2*)(out + (long)row * DD + c) = make_float2(vx, vy);
}

// ---------- conv2 agg (bf16 payload, int4-packed edges), unroll x8 ----------
__global__ __launch_bounds__(256) void k_agg_csr_b(const unsigned short* __restrict__ xwb,
    const int* __restrict__ rptr, const int4* __restrict__ ewk,
    const float* __restrict__ dinv, const float* __restrict__ b,
    float* __restrict__ out, int n){
  int row = blockIdx.x * 4 + (threadIdx.x >> 6);
  if (row >= n) return;
  int c = (threadIdx.x & 63) * 2;
  int j0 = __builtin_amdgcn_readfirstlane(rptr[row]);
  int j1 = __builtin_amdgcn_readfirstlane(rptr[row + 1]);
  float ax[8], ay[8];
  #pragma unroll
  for (int i = 0; i < 8; i++){ ax[i] = 0.f; ay[i] = 0.f; }
  int j = j0;
  for (; j + 7 < j1; j += 8){
    #pragma unroll
    for (int i = 0; i < 8; i++){
      int4 q = ewk[j + i];
      float w = __int_as_float(q.z);
      unsigned v = *(const unsigned*)(xwb + (long)q.x * DD + c);
      ax[i] += __uint_as_float(v << 16) * w;
      ay[i] += __uint_as_float(v & 0xffff0000u) * w;
    }
  }
  for (; j < j1; j++){
    int4 q = ewk[j];
    float w = __int_as_float(q.z);
    unsigned v = *(const unsigned*)(xwb + (long)q.x * DD + c);
    ax[0] += __uint_as_float(v << 16) * w;
    ay[0] += __uint_as_float(v & 0xffff0000u) * w;
  }
  float sax = ((ax[0]+ax[1])+(ax[2]+ax[3])) + ((ax[4]+ax[5])+(ax[6]+ax[7]));
  float say = ((ay[0]+ay[1])+(ay[2]+ay[3])) + ((ay[4]+ay[5])+(ay[6]+ay[7]));
  float dd = dinv[row];
  unsigned sv = *(const unsigned*)(xwb + (long)row * DD + c);
  float sx = __uint_as_float(sv << 16), sy = __uint_as_float(sv & 0xffff0000u);
  float2 bb = *(const float2*)(b + c);
  float vx = sax * dd + sx * dd * dd + bb.x;
  float vy = say * dd + sy * dd * dd + bb.y;
  vx = vx > 0.f ? vx : expm1f(vx);
  vy = vy > 0.f ? vy : expm1f(vy);
  *(float2*)(out + (long)row * DD + c) = make_float2(vx, vy);
}

// ---------- conv1 agg (sparse bf16 payload, int4-packed edges), unroll x8 ----------
__global__ __launch_bounds__(256) void k_agg_csr_sp_b(const unsigned short* __restrict__ hwb,
    const int* __restrict__ inv, const int* __restrict__ rptr,
    const int4* __restrict__ ewk,
    const float* __restrict__ dinv, const float* __restrict__ b,
    float* __restrict__ out, int n){
  int row = blockIdx.x * 4 + (threadIdx.x >> 6);
  if (row >= n) return;
  int c = (threadIdx.x & 63) * 2;
  int j0 = __builtin_amdgcn_readfirstlane(rptr[row]);
  int j1 = __builtin_amdgcn_readfirstlane(rptr[row + 1]);
  float ax[8], ay[8];
  #pragma unroll
  for (int i = 0; i < 8; i++){ ax[i] = 0.f; ay[i] = 0.f; }
  int j = j0;
  for (; j + 7 < j1; j += 8){
    #pragma unroll
    for (int i = 0; i < 8; i++){
      int4 q = ewk[j + i];
      float w = __int_as_float(q.z);
      if (q.y >= 0){
        unsigned v = *(const unsigned*)(hwb + (long)q.y * DD + c);
        ax[i] += __uint_as_float(v << 16) * w;
        ay[i] += __uint_as_float(v & 0xffff0000u) * w;
      }
    }
  }
  for (; j < j1; j++){
    int4 q = ewk[j];
    float w = __int_as_float(q.z);
    if (q.y >= 0){
      unsigned v = *(const unsigned*)(hwb + (long)q.y * DD + c);
      ax[0] += __uint_as_float(v << 16) * w;
      ay[0] += __uint_as_float(v & 0xffff0000u) * w;
    }
  }
  float sax = ((ax[0]+ax[1])+(ax[2]+ax[3])) + ((ax[4]+ax[5])+(ax[6]+ax[7]));
  float say = ((ay[0]+ay[1])+(ay[2]+ay[3])) + ((ay[4]+ay[5])+(ay[6]+ay[7]));
  float dd = dinv[row];
  int pr = inv[row];
  float sx = 0.f, sy = 0.f;
  if (pr >= 0){
    unsigned sv = *(const unsigned*)(hwb + (long)pr * DD + c);
    sx = __uint_as_float(sv << 16); sy = __uint_as_float(sv & 0xffff0000u);
  }
  float2 bb = *(const float2*)(b + c);
  float vx = sax * dd + sx * dd * dd + bb.x;
  float vy = say * dd + sy * dd * dd + bb.y;
  vx = vx > 0.f ? vx : expm1f(vx);
  vy = vy > 0.f ? vy : expm1f(vy);
  *(float2*)(out + (long)row * DD + c) = make_float2(vx, vy);
}

extern "C" void kernel_launch(void* const* d_in, const int* in_sizes, int n_in,
                              void* d_out, int out_size, void* d_ws, size_t ws_size,
                              hipStream_t stream) {
  const int*   edge   = (const int*)d_in[1];
  const float* px     = (const float*)d_in[2];
  const int*   pedge  = (const int*)d_in[3];
  const int*   unpool = (const int*)d_in[4];
  const float* W0 = (const float*)d_in[5]; const float* b0 = (const float*)d_in[6];
  const float* W1 = (const float*)d_in[7]; const float* b1 = (const float*)d_in[8];
  const float* W2 = (const float*)d_in[9]; const float* b2 = (const float*)d_in[10];
  const int n_full = in_sizes[0] / DD;
  const int E_full = in_sizes[1] / 2;
  const int n_pool = in_sizes[2] / DD;
  const int E_pool = in_sizes[3] / 2;
  float* out = (float*)d_out;

  // ---- workspace layout ----
  char* w = (char*)d_ws;
  size_t off = 0;
  auto alloc = [&](size_t bytes) -> void* {
    void* p = (void*)(w + off);
    off += (bytes + 255) / 256 * 256;
    return p;
  };
  float* dinv_p = (float*)alloc((size_t)n_pool * 4);
  float* dinv_f = (float*)alloc((size_t)n_full * 4);
  int* cnt_p  = (int*)alloc((size_t)n_pool * 4);
  int* cnt_f  = (int*)alloc((size_t)n_full * 4);
  size_t cnt_span = (size_t)((char*)(cnt_f + n_full) - (char*)cnt_p);
  int* rptr_p = (int*)alloc((size_t)(n_pool + 1) * 4);
  int* rptr_f = (int*)alloc((size_t)(n_full + 1) * 4);
  int* rank_p = (int*)alloc((size_t)E_pool * 4);
  int* rank_f = (int*)alloc((size_t)E_full * 4);
  int2* ewk_p = (int2*)alloc((size_t)E_pool * 8);
  int4* ewk_f = (int4*)alloc((size_t)E_full * 16);
  int* invm   = (int*)alloc((size_t)n_full * 4);
  const int nbf = cdiv(n_full, 1024), nbp = cdiv(n_pool, 1024);
  int* bsum_f = (int*)alloc((size_t)nbf * 4);
  int* bsum_p = (int*)alloc((size_t)nbp * 4);
  const size_t big = (size_t)n_full * DD * 4;
  float* bufA = (float*)alloc(big);
  float* bufB = (float*)alloc(big);

  const int* src_f = edge;          const int* dst_f = edge + E_full;
  const int* src_p = pedge;         const int* dst_p = pedge + E_pool;

  // ---- CSR build (both graphs) + inverse unpool map ----
  (void)hipMemsetAsync(cnt_p, 0, cnt_span, stream);
  k_count2<<<cdiv((long)E_full + E_pool + n_full,256),256,0,stream>>>(
      dst_f, E_full, cnt_f, rank_f, dst_p, E_pool, cnt_p, rank_p, invm, n_full);
  const int nbi = cdiv(n_pool, 256);
  k_bsum<<<nbf + nbp + nbi,256,0,stream>>>(cnt_f, n_full, cnt_p, n_pool, bsum_f, bsum_p,
                                           nbf, nbp, unpool, invm, n_pool);
  k_scan_b<<<1,128,0,stream>>>(bsum_f, nbf, bsum_p, nbp);
  k_scan_f<<<nbf + nbp,256,0,stream>>>(cnt_f, n_full, bsum_f, cnt_p, n_pool, bsum_p,
                                       rptr_f, dinv_f, rptr_p, dinv_p,
                                       nbf, E_full, E_pool);
  k_fill2<<<cdiv((long)E_full + E_pool,256),256,0,stream>>>(
      src_f, dst_f, E_full, rptr_f, rank_f, ewk_f, dinv_f, invm,
      src_p, dst_p, E_pool, rptr_p, rank_p, ewk_p, dinv_p);

  float* xw0 = bufA;                             // pool rows fp32
  float* h0  = bufB;                             // pool rows fp32
  unsigned short* hw1b = (unsigned short*)bufA;  // pool rows bf16 (xw0 dead)
  float* y1  = bufB;                             // full rows fp32 (h0 dead after gemm... y1 overlaps h0's buffer only after h0 consumed)
  unsigned short* xw2b = (unsigned short*)bufA;  // full rows bf16 (hw1b dead after agg_sp)

  // NOTE: y1 (bufB) overwrites h0 (bufB) — h0 is fully consumed by the conv1 GEMM
  // before k_agg_csr_sp_b writes y1 (separate dispatch, stream-ordered). Safe.

  // conv0 (pooled graph)
  k_gemm_t<false><<<cdiv(n_pool,128),256,0,stream>>>(px, W0, xw0, n_pool);
  k_agg_csr<<<cdiv(n_pool,4),256,0,stream>>>(xw0, rptr_p, ewk_p, dinv_p, b0, h0, n_pool);

  // conv1 (full graph, sparse bf16 payload)
  k_gemm_t<true><<<cdiv(n_pool,128),256,0,stream>>>(h0, W1, hw1b, n_pool);
  k_agg_csr_sp_b<<<cdiv(n_full,4),256,0,stream>>>(hw1b, invm, rptr_f, ewk_f, dinv_f, b1, y1, n_full);

  // conv2 (full graph, bf16 gather payload)
  k_gemm_t<true><<<cdiv(n_full,128),256,0,stream>>>(y1, W2, xw2b, n_full);
  k_agg_csr_b<<<cdiv(n_full,4),256,0,stream>>>(xw2b, rptr_f, ewk_f, dinv_f, b2, out, n_full);
}